// Round 9
// baseline (1141.024 us; speedup 1.0000x reference)
//
#include <hip/hip_runtime.h>
#include <math.h>

#define BS   2048
#define DIM  2048
#define NE   64
#define NF   512
#define TOPK 8
#define MAXT 320   // max (expert, m0) tiles: sum ceil(n_e/64) <= 256+64

typedef __attribute__((ext_vector_type(8))) short bf16x8;
typedef __attribute__((ext_vector_type(4))) float f32x4;

// pack 2 f32 -> 2 bf16 (RNE), lo in [15:0]
__device__ __forceinline__ unsigned cvt2(float lo, float hi) {
    unsigned r;
    asm("v_cvt_pk_bf16_f32 %0, %1, %2" : "=v"(r) : "v"(lo), "v"(hi));
    return r;
}
__device__ __forceinline__ unsigned short f2bf(float f) {
    return (unsigned short)(cvt2(f, 0.f) & 0xFFFF);
}
// 8 fp32 (two float4) -> bf16x8 fragment
__device__ __forceinline__ bf16x8 pk8(float4 lo, float4 hi) {
    union { bf16x8 v; unsigned u[4]; } r;
    r.u[0] = cvt2(lo.x, lo.y); r.u[1] = cvt2(lo.z, lo.w);
    r.u[2] = cvt2(hi.x, hi.y); r.u[3] = cvt2(hi.z, hi.w);
    return r.v;
}

// ---------------- zero out + counters ----------------
__global__ __launch_bounds__(256) void zero_kernel(float* __restrict__ out, int* __restrict__ count)
{
    const size_t idx = (size_t)blockIdx.x * blockDim.x + threadIdx.x;
    const size_t tot = (size_t)BS * DIM;
    for (size_t i = idx * 4; i < tot; i += (size_t)gridDim.x * blockDim.x * 4) {
        *(float4*)&out[i] = make_float4(0.f, 0.f, 0.f, 0.f);
    }
    if (idx < NE) count[idx] = 0;
}

// ---------------- x fp32 -> bf16 (8.4 MB, L3-resident working copy) ----------------
__global__ __launch_bounds__(256) void cvt_x_kernel(const float* __restrict__ x,
                                                    unsigned short* __restrict__ xb)
{
    const int idx = blockIdx.x * 256 + threadIdx.x;
    const int tot = BS * DIM / 4;
    for (int i = idx; i < tot; i += gridDim.x * 256) {
        const float4 v = *(const float4*)&x[i * 4];
        *(uint2*)&xb[i * 4] = make_uint2(cvt2(v.x, v.y), cvt2(v.z, v.w));
    }
}

// ---------------- router: 4 tokens/block, wave-parallel top-8 ----------------
__global__ __launch_bounds__(256) void router_kernel(
    const float* __restrict__ x, const float* __restrict__ gate_w,
    const int* __restrict__ token_mod, const int* __restrict__ expert_mod,
    int* __restrict__ count, int* __restrict__ list_token, float* __restrict__ list_w)
{
    __shared__ float xs[4 * DIM];
    __shared__ float pr[4][NE];
    const int t0  = blockIdx.x * 4;
    const int tid = threadIdx.x;
    const int lane = tid & 63, wave = tid >> 6;

    float4* xs4 = (float4*)xs;
    const float4* xr = (const float4*)(x + (size_t)t0 * DIM);
    for (int i = tid; i < 4 * (DIM / 4); i += 256) xs4[i] = xr[i];
    __syncthreads();

    for (int j = 0; j < 16; ++j) {
        const int e = wave * 16 + j;
        const float4* gw = (const float4*)(gate_w + (size_t)e * DIM);
        float s0 = 0.f, s1 = 0.f, s2 = 0.f, s3 = 0.f;
        for (int i = lane; i < DIM / 4; i += 64) {
            const float4 g  = gw[i];
            const float4 v0 = xs4[0 * 512 + i];
            const float4 v1 = xs4[1 * 512 + i];
            const float4 v2 = xs4[2 * 512 + i];
            const float4 v3 = xs4[3 * 512 + i];
            s0 += v0.x * g.x + v0.y * g.y + v0.z * g.z + v0.w * g.w;
            s1 += v1.x * g.x + v1.y * g.y + v1.z * g.z + v1.w * g.w;
            s2 += v2.x * g.x + v2.y * g.y + v2.z * g.z + v2.w * g.w;
            s3 += v3.x * g.x + v3.y * g.y + v3.z * g.z + v3.w * g.w;
        }
        #pragma unroll
        for (int off = 32; off > 0; off >>= 1) {
            s0 += __shfl_xor(s0, off, 64);
            s1 += __shfl_xor(s1, off, 64);
            s2 += __shfl_xor(s2, off, 64);
            s3 += __shfl_xor(s3, off, 64);
        }
        if (lane == 0) {
            pr[0][e] = s0; pr[1][e] = s1; pr[2][e] = s2; pr[3][e] = s3;
        }
    }
    __syncthreads();

    {
        const int t  = t0 + wave;
        const int tm = token_mod[t];
        const int em = expert_mod[lane];
        float p = pr[wave][lane];
        if (tm * em == -1) p = -INFINITY;
        float m0 = p;
        #pragma unroll
        for (int off = 32; off > 0; off >>= 1) m0 = fmaxf(m0, __shfl_xor(m0, off, 64));
        p = __expf(p - m0);                  // exp(-inf)=0; softmax denom cancels in renorm
        float s8 = 0.f, wsel = 0.f;
        int   esel = 0;
        #pragma unroll
        for (int k = 0; k < TOPK; ++k) {
            float m = p;
            #pragma unroll
            for (int off = 32; off > 0; off >>= 1) m = fmaxf(m, __shfl_xor(m, off, 64));
            const unsigned long long b = __ballot(p == m);
            const int bi = __ffsll((unsigned long long)b) - 1;   // lowest index on ties
            if (lane == bi) p = -1.f;
            if (lane == k) { esel = bi; wsel = m; }
            s8 += m;
        }
        const float inv = 1.f / s8;
        if (lane < TOPK) {
            const int pos = atomicAdd(&count[esel], 1);
            list_token[esel * BS + pos] = t;
            list_w[esel * BS + pos]     = wsel * inv;
        }
    }
}

// ---------------- scan + compacted (expert, m0) worklist ----------------
__global__ void scan_kernel(const int* __restrict__ count, int* __restrict__ offsets,
                            int* __restrict__ worklist, int* __restrict__ ntiles)
{
    if (threadIdx.x == 0) {
        int s = 0, nt = 0;
        for (int e = 0; e < NE; ++e) {
            offsets[e] = s;
            for (int m0 = 0; m0 < count[e]; m0 += 64) worklist[nt++] = (e << 16) | m0;
            s += count[e];
        }
        ntiles[0] = nt;
    }
}

struct B8 { float4 v[8]; };

// ---------------- gate/up: barrier-free streaming MFMA GEMM -> h (bf16) ----------------
// block 64 tok x 64 f, 4 waves; wave = 32 tok x 32 f (gate AND up). BK=32, 64 steps.
// Weights fp32 direct-to-reg (1-step named-buffer prefetch); X bf16 16B gathers (L1/L3).
// No LDS, no barriers in the main loop: waves are independent streams.

#define GU_LOADB(BUF, KO)                                                     \
    {                                                                         \
        _Pragma("unroll")                                                     \
        for (int nn = 0; nn < 2; ++nn) {                                      \
            (BUF).v[nn * 2 + 0] = *(const float4*)(gp[nn] + (KO));            \
            (BUF).v[nn * 2 + 1] = *(const float4*)(gp[nn] + (KO) + 4);        \
            (BUF).v[4 + nn * 2 + 0] = *(const float4*)(up[nn] + (KO));        \
            (BUF).v[4 + nn * 2 + 1] = *(const float4*)(up[nn] + (KO) + 4);    \
        }                                                                     \
    }

#define GU_STEP(BUF, KO)                                                      \
    {                                                                         \
        bf16x8 a[2], bg[2], bu[2];                                            \
        _Pragma("unroll")                                                     \
        for (int m = 0; m < 2; ++m) a[m] = *(const bf16x8*)(aptr[m] + (KO));  \
        _Pragma("unroll")                                                     \
        for (int nn = 0; nn < 2; ++nn) {                                      \
            bg[nn] = pk8((BUF).v[nn * 2], (BUF).v[nn * 2 + 1]);               \
            bu[nn] = pk8((BUF).v[4 + nn * 2], (BUF).v[4 + nn * 2 + 1]);       \
        }                                                                     \
        _Pragma("unroll")                                                     \
        for (int m = 0; m < 2; ++m)                                           \
            _Pragma("unroll")                                                 \
            for (int nn = 0; nn < 2; ++nn) {                                  \
                accg[m][nn] = __builtin_amdgcn_mfma_f32_16x16x32_bf16(a[m], bg[nn], accg[m][nn], 0, 0, 0); \
                accu[m][nn] = __builtin_amdgcn_mfma_f32_16x16x32_bf16(a[m], bu[nn], accu[m][nn], 0, 0, 0); \
            }                                                                 \
    }

__global__ __launch_bounds__(256, 2) void gateup_mfma(
    const unsigned short* __restrict__ xb,
    const float* __restrict__ w_gate, const float* __restrict__ w_up,
    const int* __restrict__ count, const int* __restrict__ offsets,
    const int* __restrict__ worklist, const int* __restrict__ ntiles,
    const int* __restrict__ list_token, const float* __restrict__ list_w,
    unsigned short* __restrict__ h)
{
    if ((int)blockIdx.y >= ntiles[0]) return;
    const int wl = worklist[blockIdx.y];
    const int e  = wl >> 16;
    const int m0 = wl & 0xFFFF;
    const int f0 = blockIdx.x * 64;
    const int mc = min(64, count[e] - m0);

    const int tid = threadIdx.x;
    const int lane = tid & 63, wave = tid >> 6;
    const int wr = wave >> 1, wc = wave & 1;
    const int kq = (lane >> 4) * 8;   // k sub-window (8 elems)

    // A sources: this lane's two token rows (clamped), bf16
    const unsigned short* aptr[2];
    #pragma unroll
    for (int m = 0; m < 2; ++m) {
        const int r = wr * 32 + m * 16 + (lane & 15);
        const int t = list_token[e * BS + m0 + (r < mc ? r : 0)];
        aptr[m] = xb + (size_t)t * DIM + kq;
    }
    // B sources: this lane's f rows in w_gate / w_up, fp32
    const float* gp[2];
    const float* up[2];
    #pragma unroll
    for (int nn = 0; nn < 2; ++nn) {
        const int fr = f0 + wc * 32 + nn * 16 + (lane & 15);
        gp[nn] = w_gate + (size_t)e * NF * DIM + (size_t)fr * DIM + kq;
        up[nn] = w_up   + (size_t)e * NF * DIM + (size_t)fr * DIM + kq;
    }

    f32x4 accg[2][2] = {};
    f32x4 accu[2][2] = {};
    B8 bufA, bufB;

    GU_LOADB(bufA, 0);
    for (int t = 0; t < DIM / 32; t += 2) {
        GU_LOADB(bufB, (t + 1) * 32);
        GU_STEP(bufA, t * 32);
        if (t + 2 < DIM / 32) GU_LOADB(bufA, (t + 2) * 32);
        GU_STEP(bufB, (t + 1) * 32);
    }

    const int base = offsets[e] + m0;
    #pragma unroll
    for (int m = 0; m < 2; ++m) {
        #pragma unroll
        for (int j = 0; j < 4; ++j) {
            const int tl = wr * 32 + m * 16 + (lane >> 4) * 4 + j;
            if (tl < mc) {
                const float w = list_w[e * BS + m0 + tl];
                #pragma unroll
                for (int nn = 0; nn < 2; ++nn) {
                    const int fl = f0 + wc * 32 + nn * 16 + (lane & 15);
                    const float g  = accg[m][nn][j];
                    const float u  = accu[m][nn][j];
                    const float hv = w * u * (g / (1.f + __expf(-g)));
                    h[(size_t)(base + tl) * NF + fl] = f2bf(hv);
                }
            }
        }
    }
}

// ---------------- down: barrier-free streaming MFMA GEMM + atomic combine ----------------
// block 64 slots x 128 d, 4 waves; wave = 32 slots x 64 d. BK=32 over F, 16 steps.

#define DK_LOADB(BUF, KO)                                                     \
    {                                                                         \
        _Pragma("unroll")                                                     \
        for (int nn = 0; nn < 4; ++nn) {                                      \
            (BUF).v[nn * 2 + 0] = *(const float4*)(bp[nn] + (KO));            \
            (BUF).v[nn * 2 + 1] = *(const float4*)(bp[nn] + (KO) + 4);        \
        }                                                                     \
    }

#define DK_STEP(BUF, KO)                                                      \
    {                                                                         \
        bf16x8 a[2], b[4];                                                    \
        _Pragma("unroll")                                                     \
        for (int m = 0; m < 2; ++m) a[m] = *(const bf16x8*)(aptr[m] + (KO));  \
        _Pragma("unroll")                                                     \
        for (int nn = 0; nn < 4; ++nn)                                        \
            b[nn] = pk8((BUF).v[nn * 2], (BUF).v[nn * 2 + 1]);                \
        _Pragma("unroll")                                                     \
        for (int m = 0; m < 2; ++m)                                           \
            _Pragma("unroll")                                                 \
            for (int nn = 0; nn < 4; ++nn)                                    \
                acc[m][nn] = __builtin_amdgcn_mfma_f32_16x16x32_bf16(a[m], b[nn], acc[m][nn], 0, 0, 0); \
    }

__global__ __launch_bounds__(256, 2) void down_mfma(
    const float* __restrict__ w_down,
    const int* __restrict__ count, const int* __restrict__ offsets,
    const int* __restrict__ worklist, const int* __restrict__ ntiles,
    const int* __restrict__ list_token,
    const unsigned short* __restrict__ h, float* __restrict__ out)
{
    if ((int)blockIdx.y >= ntiles[0]) return;
    const int wl = worklist[blockIdx.y];
    const int e  = wl >> 16;
    const int m0 = wl & 0xFFFF;
    const int d0 = blockIdx.x * 128;
    const int mc = min(64, count[e] - m0);

    const int tid = threadIdx.x;
    const int lane = tid & 63, wave = tid >> 6;
    const int wr = wave >> 1, wc = wave & 1;
    const int kq = (lane >> 4) * 8;
    const int base = offsets[e] + m0;

    // A sources: h rows (bf16)
    const unsigned short* aptr[2];
    #pragma unroll
    for (int m = 0; m < 2; ++m) {
        const int r = wr * 32 + m * 16 + (lane & 15);
        aptr[m] = h + (size_t)(base + (r < mc ? r : 0)) * NF + kq;
    }
    // B sources: w_down rows (fp32)
    const float* bp[4];
    #pragma unroll
    for (int nn = 0; nn < 4; ++nn) {
        const int dr = d0 + wc * 64 + nn * 16 + (lane & 15);
        bp[nn] = w_down + (size_t)e * DIM * NF + (size_t)dr * NF + kq;
    }

    f32x4 acc[2][4] = {};
    B8 bufA, bufB;

    DK_LOADB(bufA, 0);
    for (int t = 0; t < NF / 32; t += 2) {
        DK_LOADB(bufB, (t + 1) * 32);
        DK_STEP(bufA, t * 32);
        if (t + 2 < NF / 32) DK_LOADB(bufA, (t + 2) * 32);
        DK_STEP(bufB, (t + 1) * 32);
    }

    #pragma unroll
    for (int m = 0; m < 2; ++m)
        #pragma unroll
        for (int j = 0; j < 4; ++j) {
            const int sl = wr * 32 + m * 16 + (lane >> 4) * 4 + j;
            if (sl < mc) {
                const int tok = list_token[e * BS + m0 + sl];
                float* orow = out + (size_t)tok * DIM + d0 + wc * 64 + (lane & 15);
                #pragma unroll
                for (int nn = 0; nn < 4; ++nn)
                    atomicAdd(&orow[nn * 16], acc[m][nn][j]);
            }
        }
}

extern "C" void kernel_launch(void* const* d_in, const int* in_sizes, int n_in,
                              void* d_out, int out_size, void* d_ws, size_t ws_size,
                              hipStream_t stream)
{
    const float* x          = (const float*)d_in[0];
    const float* gate_w     = (const float*)d_in[1];
    const float* w_gate     = (const float*)d_in[2];
    const float* w_up       = (const float*)d_in[3];
    const float* w_down     = (const float*)d_in[4];
    const int*   token_mod  = (const int*)d_in[5];
    const int*   expert_mod = (const int*)d_in[6];
    float* out = (float*)d_out;

    // ws: h bf16 16 MB | x_bf16 8 MB | count | offsets | ntiles | worklist | list_token | list_w
    char* ws = (char*)d_ws;
    unsigned short* h  = (unsigned short*)ws;                       // 16,777,216 B
    unsigned short* xb = (unsigned short*)(ws + 16777216);          //  8,388,608 B
    int*   count      = (int*)(ws + 25165824);                      // 256 B
    int*   offsets    = (int*)(ws + 25166080);                      // 256 B
    int*   ntiles     = (int*)(ws + 25166336);                      // 256 B
    int*   worklist   = (int*)(ws + 25166592);                      // 2048 B
    int*   list_token = (int*)(ws + 25168640);                      // 524,288 B
    float* list_w     = (float*)(ws + 25692928);                    // 524,288 B

    zero_kernel<<<2048, 256, 0, stream>>>(out, count);
    cvt_x_kernel<<<1024, 256, 0, stream>>>(x, xb);
    router_kernel<<<BS / 4, 256, 0, stream>>>(x, gate_w, token_mod, expert_mod,
                                              count, list_token, list_w);
    scan_kernel<<<1, 64, 0, stream>>>(count, offsets, worklist, ntiles);

    dim3 g1(NF / 64, MAXT);    // (8, 320)
    gateup_mfma<<<g1, 256, 0, stream>>>(xb, w_gate, w_up, count, offsets,
                                        worklist, ntiles, list_token, list_w, h);
    dim3 g2(DIM / 128, MAXT);  // (16, 320)
    down_mfma<<<g2, 256, 0, stream>>>(w_down, count, offsets, worklist, ntiles,
                                      list_token, h, out);
}